// Round 2
// baseline (1030.056 us; speedup 1.0000x reference)
//
#include <hip/hip_runtime.h>
#include <hip/hip_fp16.h>

typedef _Float16 f16;
typedef __attribute__((ext_vector_type(8))) _Float16 f16x8;
typedef __attribute__((ext_vector_type(4))) _Float16 f16x4;
typedef __attribute__((ext_vector_type(4))) float f32x4;

#define NSEG 50000
#define DIM 128
#define LDST 136   // f16 elems per LDS row: 128 + 8 pad
#define CHUNK 16   // tiles per persistent phi block

#define MFMA16(a, b, c) __builtin_amdgcn_mfma_f32_16x16x32_f16((a), (b), (c), 0, 0, 0)

// ---------------- setup: zero seg_sum+counts AND prepack weights, one launch --------
// blocks [0, zblk): zero-fill.  blocks [zblk, zblk+32): prepack.
__global__ void setup_kernel(float4* __restrict__ za, int n4a,
                             float4* __restrict__ zb, int n4b, int zblk,
                             const float* __restrict__ w0, const float* __restrict__ w1,
                             const float* __restrict__ w2, const float* __restrict__ w3,
                             f16* __restrict__ packs) {
    int b = blockIdx.x;
    int tid = threadIdx.x;
    if (b < zblk) {
        int i = b * 256 + tid;
        float4 z = make_float4(0.f, 0.f, 0.f, 0.f);
        if (i < n4a) {
            za[i] = z;
        } else {
            int j = i - n4a;
            if (j < n4b) zb[j] = z;
        }
        return;
    }
    // prepack: W^T in A-fragment order.
    // A-frag (16x16x32): lane holds A[m'][k], m' = tm*16 + (lane&15),
    // k = kt*32 + (lane>>4)*8 + j.  pack[q][((tm*4+kt)*64+lane)*8+j] = W[k][m']
    int gid = (b - zblk) * 256 + tid;   // [0, 8192)
    int q = gid >> 11;
    int r = gid & 2047;
    int tm = r >> 8;
    int kt = (r >> 6) & 3;
    int lane = r & 63;
    const float* W = (q == 0) ? w0 : (q == 1) ? w1 : (q == 2) ? w2 : w3;
    int mp = tm * 16 + (lane & 15);
    int kb = kt * 32 + ((lane >> 4) & 3) * 8;
    f16* dst = packs + q * 16384 + ((size_t)((tm * 4 + kt) * 64 + lane)) * 8;
#pragma unroll
    for (int j = 0; j < 8; ++j)
        dst[j] = (f16)W[(size_t)(kb + j) * DIM + mp];
}

// ---------------- phi staging helpers ----------------
__device__ __forceinline__ void stage_load(const float* __restrict__ x,
                                           const int* __restrict__ batch,
                                           int tile, int N, int tid,
                                           float4 xs[16], int& sv) {
    int r0 = tile * 128;
    int nvalid = min(128, N - r0);
#pragma unroll
    for (int i = 0; i < 16; ++i) {
        int flat = i * 1024 + tid * 4;
        int row = flat >> 7, col = flat & 127;
        xs[i] = make_float4(0.f, 0.f, 0.f, 0.f);
        if (row < nvalid) xs[i] = *(const float4*)(x + (size_t)(r0 + row) * DIM + col);
    }
    sv = -1;
    if (tid < 128 && tid < nvalid) {
        int s = batch[r0 + tid];                              // int32 per harness
        sv = (s < 0) ? 0 : ((s >= NSEG) ? NSEG - 1 : s);      // fault insurance
    }
}

__device__ __forceinline__ void stage_write(f16* __restrict__ bufc, int* __restrict__ segc,
                                            int tid, const float4 xs[16], int sv) {
#pragma unroll
    for (int i = 0; i < 16; ++i) {
        int flat = i * 1024 + tid * 4;
        int row = flat >> 7, col = flat & 127;
        f16x4 h;
        h[0] = (f16)xs[i].x; h[1] = (f16)xs[i].y; h[2] = (f16)xs[i].z; h[3] = (f16)xs[i].w;
        *(f16x4*)(bufc + row * LDST + col) = h;
    }
    if (tid < 128) segc[tid] = sv;
}

// ---------------- phi MLP + fused sorted-segment scatter-sum (persistent) ----------
// Double-buffered LDS (2 x 34.8KB -> 2 blocks/CU). Each iteration issues the NEXT
// tile's global loads into registers BEFORE computing the current tile, so the HBM
// stream never idles behind the barrier-locked compute/walk phases.
__global__ __launch_bounds__(256, 2)
void phi_scatter_kernel(const float* __restrict__ x, const int* __restrict__ batch,
                        const f16* __restrict__ pack1, const f16* __restrict__ pack2,
                        const float* __restrict__ b1, const float* __restrict__ b2,
                        float* __restrict__ seg_sum, float* __restrict__ counts,
                        int N, int ntiles) {
    __shared__ f16 buf[2][128 * LDST];   // 69,632 B
    __shared__ int seg_s[2][128];

    int tid = threadIdx.x;
    int wave = tid >> 6, lane = tid & 63, g = lane >> 4, ln = lane & 15;
    int tm0 = wave * 2;

    int start = blockIdx.x * CHUNK;
    int cnt_t = min(CHUNK, ntiles - start);
    if (cnt_t <= 0) return;

    // prologue: stage first tile into buf[0]
    {
        float4 xs[16]; int sv;
        stage_load(x, batch, start, N, tid, xs, sv);
        stage_write(buf[0], seg_s[0], tid, xs, sv);
    }
    __syncthreads();

    int cur = 0;
    for (int t = 0; t < cnt_t; ++t) {
        bool have_next = (t + 1 < cnt_t);
        float4 xs[16]; int sv = -1;
        if (have_next) stage_load(x, batch, start + t + 1, N, tid, xs, sv);

        f16* bc = buf[cur];
        int* sc = seg_s[cur];

        f32x4 acc[2][8];
#pragma unroll
        for (int a = 0; a < 2; ++a)
#pragma unroll
            for (int tt = 0; tt < 8; ++tt) acc[a][tt] = (f32x4){0.f, 0.f, 0.f, 0.f};

        // GEMM1: h1^T = W1^T * x^T
#pragma unroll
        for (int kt = 0; kt < 4; ++kt) {
            f16x8 a0 = *(const f16x8*)(pack1 + ((size_t)((tm0 + 0) * 4 + kt) * 64 + lane) * 8);
            f16x8 a1 = *(const f16x8*)(pack1 + ((size_t)((tm0 + 1) * 4 + kt) * 64 + lane) * 8);
#pragma unroll
            for (int tn = 0; tn < 8; ++tn) {
                f16x8 b = *(const f16x8*)(bc + (tn * 16 + ln) * LDST + kt * 32 + g * 8);
                acc[0][tn] = MFMA16(a0, b, acc[0][tn]);
                acc[1][tn] = MFMA16(a1, b, acc[1][tn]);
            }
        }
        __syncthreads();

        // epilogue1: relu(c + b1) -> bc (B-operand layout for GEMM2)
#pragma unroll
        for (int a = 0; a < 2; ++a) {
            int tm = tm0 + a;
            float4 bv = *(const float4*)(b1 + tm * 16 + g * 4);
#pragma unroll
            for (int tn = 0; tn < 8; ++tn) {
                f32x4 c = acc[a][tn];
                f16x4 h;
                h[0] = (f16)fmaxf(c[0] + bv.x, 0.f);
                h[1] = (f16)fmaxf(c[1] + bv.y, 0.f);
                h[2] = (f16)fmaxf(c[2] + bv.z, 0.f);
                h[3] = (f16)fmaxf(c[3] + bv.w, 0.f);
                *(f16x4*)(bc + (tn * 16 + ln) * LDST + tm * 16 + g * 4) = h;
            }
        }
        __syncthreads();

        // GEMM2: h^T = W2^T * h1^T
#pragma unroll
        for (int a = 0; a < 2; ++a)
#pragma unroll
            for (int tt = 0; tt < 8; ++tt) acc[a][tt] = (f32x4){0.f, 0.f, 0.f, 0.f};
#pragma unroll
        for (int kt = 0; kt < 4; ++kt) {
            f16x8 a0 = *(const f16x8*)(pack2 + ((size_t)((tm0 + 0) * 4 + kt) * 64 + lane) * 8);
            f16x8 a1 = *(const f16x8*)(pack2 + ((size_t)((tm0 + 1) * 4 + kt) * 64 + lane) * 8);
#pragma unroll
            for (int tn = 0; tn < 8; ++tn) {
                f16x8 b = *(const f16x8*)(bc + (tn * 16 + ln) * LDST + kt * 32 + g * 8);
                acc[0][tn] = MFMA16(a0, b, acc[0][tn]);
                acc[1][tn] = MFMA16(a1, b, acc[1][tn]);
            }
        }
        __syncthreads();

        // epilogue2: h = c + b2 -> bc (walk layout)
#pragma unroll
        for (int a = 0; a < 2; ++a) {
            int tm = tm0 + a;
            float4 bv = *(const float4*)(b2 + tm * 16 + g * 4);
#pragma unroll
            for (int tn = 0; tn < 8; ++tn) {
                f32x4 c = acc[a][tn];
                f16x4 h;
                h[0] = (f16)(c[0] + bv.x);
                h[1] = (f16)(c[1] + bv.y);
                h[2] = (f16)(c[2] + bv.z);
                h[3] = (f16)(c[3] + bv.w);
                *(f16x4*)(bc + (tn * 16 + ln) * LDST + tm * 16 + g * 4) = h;
            }
        }
        __syncthreads();

        // sorted-segment walk: thread = (column n, half of 64 rows); 8x8 grouped
        // prefetch, fixed trip count, sentinel -1 for invalid rows.
        {
            int n = tid & 127, half = tid >> 7;
            int m0h = half * 64;
            float accv = 0.f, cntv = 0.f;
            int curs = sc[m0h];
#pragma unroll
            for (int grp = 0; grp < 8; ++grp) {
                float v[8];
                int s[8];
#pragma unroll
                for (int j = 0; j < 8; ++j) {
                    int m = m0h + grp * 8 + j;
                    s[j] = sc[m];
                    v[j] = (float)bc[m * LDST + n];
                }
#pragma unroll
                for (int j = 0; j < 8; ++j) {
                    if (s[j] != curs) {
                        if (curs >= 0) {
                            atomicAdd(seg_sum + (size_t)curs * DIM + n, accv);
                            if (n == 0) atomicAdd(counts + curs, cntv);
                        }
                        accv = 0.f; cntv = 0.f; curs = s[j];
                    }
                    accv += v[j]; cntv += 1.f;
                }
            }
            if (curs >= 0) {
                atomicAdd(seg_sum + (size_t)curs * DIM + n, accv);
                if (n == 0) atomicAdd(counts + curs, cntv);
            }
        }

        // write the prefetched next tile into the other buffer
        if (have_next) stage_write(buf[cur ^ 1], seg_s[cur ^ 1], tid, xs, sv);
        __syncthreads();
        cur ^= 1;
    }
}

// ---------------- rho MLP on segment means (IN-PLACE: seg_sum aliases out) ---------
#define RROWS 64
__global__ __launch_bounds__(256, 4)
void rho_kernel(const float* __restrict__ seg_sum, const float* __restrict__ counts,
                const f16* __restrict__ pack1, const f16* __restrict__ pack2,
                const float* __restrict__ b1, const float* __restrict__ b2,
                float* __restrict__ out) {
    __shared__ f16 buf[RROWS * LDST];  // 17,408 B

    int tid = threadIdx.x;
    int wave = tid >> 6, lane = tid & 63, g = lane >> 4, ln = lane & 15;
    int s0 = blockIdx.x * RROWS;
    int nvalid = min(RROWS, NSEG - s0);

    // stage seg_mean -> f16 LDS (reads complete before any in-place writes below)
#pragma unroll
    for (int i = 0; i < 8; ++i) {
        int flat = i * 1024 + tid * 4;
        int row = flat >> 7, col = flat & 127;
        float4 v = make_float4(0.f, 0.f, 0.f, 0.f);
        if (row < nvalid) {
            v = *(const float4*)(seg_sum + (size_t)(s0 + row) * DIM + col);
            float inv = 1.f / fmaxf(counts[s0 + row], 1.f);
            v.x *= inv; v.y *= inv; v.z *= inv; v.w *= inv;
        }
        f16x4 h;
        h[0] = (f16)v.x; h[1] = (f16)v.y; h[2] = (f16)v.z; h[3] = (f16)v.w;
        *(f16x4*)(buf + row * LDST + col) = h;
    }
    __syncthreads();

    int tm0 = wave * 2;
    f32x4 acc[2][4];
#pragma unroll
    for (int a = 0; a < 2; ++a)
#pragma unroll
        for (int t = 0; t < 4; ++t) acc[a][t] = (f32x4){0.f, 0.f, 0.f, 0.f};

#pragma unroll
    for (int kt = 0; kt < 4; ++kt) {
        f16x8 a0 = *(const f16x8*)(pack1 + ((size_t)((tm0 + 0) * 4 + kt) * 64 + lane) * 8);
        f16x8 a1 = *(const f16x8*)(pack1 + ((size_t)((tm0 + 1) * 4 + kt) * 64 + lane) * 8);
#pragma unroll
        for (int tn = 0; tn < 4; ++tn) {
            f16x8 b = *(const f16x8*)(buf + (tn * 16 + ln) * LDST + kt * 32 + g * 8);
            acc[0][tn] = MFMA16(a0, b, acc[0][tn]);
            acc[1][tn] = MFMA16(a1, b, acc[1][tn]);
        }
    }
    __syncthreads();

#pragma unroll
    for (int a = 0; a < 2; ++a) {
        int tm = tm0 + a;
        float4 bv = *(const float4*)(b1 + tm * 16 + g * 4);
#pragma unroll
        for (int tn = 0; tn < 4; ++tn) {
            f32x4 c = acc[a][tn];
            f16x4 h;
            h[0] = (f16)fmaxf(c[0] + bv.x, 0.f);
            h[1] = (f16)fmaxf(c[1] + bv.y, 0.f);
            h[2] = (f16)fmaxf(c[2] + bv.z, 0.f);
            h[3] = (f16)fmaxf(c[3] + bv.w, 0.f);
            *(f16x4*)(buf + (tn * 16 + ln) * LDST + tm * 16 + g * 4) = h;
        }
    }
    __syncthreads();

#pragma unroll
    for (int a = 0; a < 2; ++a)
#pragma unroll
        for (int t = 0; t < 4; ++t) acc[a][t] = (f32x4){0.f, 0.f, 0.f, 0.f};
#pragma unroll
    for (int kt = 0; kt < 4; ++kt) {
        f16x8 a0 = *(const f16x8*)(pack2 + ((size_t)((tm0 + 0) * 4 + kt) * 64 + lane) * 8);
        f16x8 a1 = *(const f16x8*)(pack2 + ((size_t)((tm0 + 1) * 4 + kt) * 64 + lane) * 8);
#pragma unroll
        for (int tn = 0; tn < 4; ++tn) {
            f16x8 b = *(const f16x8*)(buf + (tn * 16 + ln) * LDST + kt * 32 + g * 8);
            acc[0][tn] = MFMA16(a0, b, acc[0][tn]);
            acc[1][tn] = MFMA16(a1, b, acc[1][tn]);
        }
    }

    // epilogue: out[s][feat] = c + b2, coalesced float4 stores (in-place over seg_sum)
#pragma unroll
    for (int a = 0; a < 2; ++a) {
        int tm = tm0 + a;
        float4 bv = *(const float4*)(b2 + tm * 16 + g * 4);
#pragma unroll
        for (int tn = 0; tn < 4; ++tn) {
            int srow = tn * 16 + ln;
            if (s0 + srow < NSEG) {
                f32x4 c = acc[a][tn];
                float4 o = make_float4(c[0] + bv.x, c[1] + bv.y, c[2] + bv.z, c[3] + bv.w);
                *(float4*)(out + (size_t)(s0 + srow) * DIM + tm * 16 + g * 4) = o;
            }
        }
    }
}

extern "C" void kernel_launch(void* const* d_in, const int* in_sizes, int n_in,
                              void* d_out, int out_size, void* d_ws, size_t ws_size,
                              hipStream_t stream) {
    const float* ins = (const float*)d_in[0];
    const int* batch = (const int*)d_in[1];   // harness delivers integer inputs as int32
    // d_in[2] = dim (unused, always 0)
    const float* phi_W1 = (const float*)d_in[3];
    const float* phi_b1 = (const float*)d_in[4];
    const float* phi_W2 = (const float*)d_in[5];
    const float* phi_b2 = (const float*)d_in[6];
    const float* rho_W1 = (const float*)d_in[7];
    const float* rho_b1 = (const float*)d_in[8];
    const float* rho_W2 = (const float*)d_in[9];
    const float* rho_b2 = (const float*)d_in[10];

    int N = in_sizes[0] / DIM;  // 1,000,000

    // seg_sum lives IN d_out (50000*128 fp32 = 25.6 MB): rho_kernel stages each
    // 64-row tile to LDS before overwriting the same rows -> in-place safe.
    float* seg_sum = (float*)d_out;
    char* ws = (char*)d_ws;
    float* counts = (float*)ws;           // 200,000 B
    f16*   packs  = (f16*)(ws + 200704);  // 4 * 32,768 B; total ws use ~331 KB

    // setup: zero accumulators + prepack weights in ONE launch (graph-capture-safe)
    int n4a = NSEG * DIM / 4;   // 1,600,000
    int n4b = NSEG / 4;         // 12,500
    int zblk = (n4a + n4b + 255) / 256;   // 6,299
    setup_kernel<<<zblk + 32, 256, 0, stream>>>((float4*)seg_sum, n4a,
                                                (float4*)counts, n4b, zblk,
                                                phi_W1, phi_W2, rho_W1, rho_W2, packs);

    int ntiles = (N + 127) / 128;                       // 7,813
    int nblk = (ntiles + CHUNK - 1) / CHUNK;            // 489 (all resident at 2/CU)
    phi_scatter_kernel<<<nblk, 256, 0, stream>>>(ins, batch, packs, packs + 16384,
                                                 phi_b1, phi_b2, seg_sum, counts,
                                                 N, ntiles);

    rho_kernel<<<(NSEG + RROWS - 1) / RROWS, 256, 0, stream>>>(seg_sum, counts,
                                                       packs + 2 * 16384, packs + 3 * 16384,
                                                       rho_b1, rho_b2, (float*)d_out);
}